// Round 7
// baseline (127.704 us; speedup 1.0000x reference)
//
#include <hip/hip_runtime.h>
#include <hip/hip_bf16.h>
#include <stdint.h>

typedef __attribute__((ext_vector_type(4))) float f32x4;
typedef __attribute__((ext_vector_type(16))) float f32x16;
typedef __attribute__((ext_vector_type(8))) short bf16x8;
typedef __attribute__((ext_vector_type(4))) short bf16x4;
typedef unsigned short ushort_t;

#define QSCALE 0.18033688f   // 0.125 * log2(e): softmax runs in exp2 domain

__device__ inline short f2bf(float f) {
  unsigned u = __builtin_bit_cast(unsigned, f);
  u += 0x7fffu + ((u >> 16) & 1u);   // RNE
  return (short)(u >> 16);
}

__device__ inline float bf2f(short s) {
  return __builtin_bit_cast(float, ((unsigned)(ushort_t)s) << 16);
}

__device__ inline void gload_lds16(const void* g, void* l) {
  __builtin_amdgcn_global_load_lds(
      (const __attribute__((address_space(1))) void*)g,
      (__attribute__((address_space(3))) void*)l, 16, 0, 0);
}

__device__ inline unsigned cvtpk(float a, float b) {
  unsigned r;
  asm("v_cvt_pk_bf16_f32 %0, %1, %2" : "=v"(r) : "v"(a), "v"(b));
  return r;
}

__device__ inline void swap32u(unsigned& a, unsigned& b) {
  asm("v_permlane32_swap_b32 %0, %1" : "+v"(a), "+v"(b));
}

// ---------------- fused fp32 -> bf16 convert (x, w_qkv, w_proj) ----------------
__global__ __launch_bounds__(256) void cvt_all(const float* __restrict__ x,
                                               const float* __restrict__ wq,
                                               const float* __restrict__ wp,
                                               short* __restrict__ Xb,
                                               short* __restrict__ Wq,
                                               short* __restrict__ Wp) {
  int i = blockIdx.x * 256 + threadIdx.x;   // vec8 index, total 1048576
  const float* s;
  short* d;
  int off;
  if (i < 524288)       { s = x;  d = Xb; off = i; }
  else if (i < 917504)  { s = wq; d = Wq; off = i - 524288; }
  else                  { s = wp; d = Wp; off = i - 917504; }
  const float4* sv = (const float4*)s;
  float4 a = sv[2 * off], b = sv[2 * off + 1];
  bf16x8 o;
  o[0] = f2bf(a.x); o[1] = f2bf(a.y); o[2] = f2bf(a.z); o[3] = f2bf(a.w);
  o[4] = f2bf(b.x); o[5] = f2bf(b.y); o[6] = f2bf(b.z); o[7] = f2bf(b.w);
  ((bf16x8*)d)[off] = o;
}

// ---------------- 128xBN BK=32 3-buffer counted-vmcnt GEMM: C = A * B^T ----------------
template <int BN, int F32OUT>
__global__ __launch_bounds__(256, 3) void gemm_pipe(const short* __restrict__ A,
                                                    const short* __restrict__ B,
                                                    void* __restrict__ Cv,
                                                    const float* __restrict__ bias,
                                                    int scale_cols, float scale_val,
                                                    int M, int N, int K) {
  constexpr int MFR = (BN == 128) ? 4 : 2;
  __shared__ short Abuf[3][128 * 32];
  __shared__ short Bbuf[3][BN * 32];
  const int tid = threadIdx.x, wv = tid >> 6, ln = tid & 63;
  const int wm = (BN == 128) ? (wv >> 1) : wv;
  const int wn = (BN == 128) ? (wv & 1) : 0;
  const int bn0 = blockIdx.x * BN, bm0 = blockIdx.y * 128;
  const int nt = K >> 5;

  const int srow = ln >> 2;
  const int scol = (((ln & 3) ^ (srow & 3)) * 8);
  const int fln = ln & 15;
  const int fk = ln >> 4;

  f32x4 acc[MFR][4] = {};

  auto stage = [&](int t, int s) {
    const size_t k0 = (size_t)(t << 5);
#pragma unroll
    for (int rd = 0; rd < 2; rd++) {
      int ch = 2 * wv + rd;
      gload_lds16(A + (size_t)(bm0 + ch * 16 + srow) * K + k0 + scol,
                  (char*)Abuf[s] + ch * 1024);
    }
    if constexpr (BN == 128) {
#pragma unroll
      for (int rd = 0; rd < 2; rd++) {
        int ch = 2 * wv + rd;
        gload_lds16(B + (size_t)(bn0 + ch * 16 + srow) * K + k0 + scol,
                    (char*)Bbuf[s] + ch * 1024);
      }
    } else {
      gload_lds16(B + (size_t)(bn0 + wv * 16 + srow) * K + k0 + scol,
                  (char*)Bbuf[s] + wv * 1024);
    }
  };

  stage(0, 0);
  stage(1, 1);
  if constexpr (BN == 128) asm volatile("s_waitcnt vmcnt(4)" ::: "memory");
  else                     asm volatile("s_waitcnt vmcnt(3)" ::: "memory");
  __builtin_amdgcn_s_barrier();
  __builtin_amdgcn_sched_barrier(0);

  for (int t = 0; t < nt; t++) {
    const int s = t % 3;
    const bool more = (t + 2) < nt;
    if (more) stage(t + 2, (t + 2) % 3);

    const char* Ab = (const char*)Abuf[s];
    const char* Bb = (const char*)Bbuf[s];
    bf16x8 af[MFR], bfr[4];
#pragma unroll
    for (int m = 0; m < MFR; m++) {
      int R = wm * (MFR * 16) + m * 16 + fln;
      af[m] = *(const bf16x8*)(Ab + R * 64 + ((fk ^ (R & 3)) << 4));
    }
#pragma unroll
    for (int n = 0; n < 4; n++) {
      int R = wn * 64 + n * 16 + fln;
      bfr[n] = *(const bf16x8*)(Bb + R * 64 + ((fk ^ (R & 3)) << 4));
    }

    __builtin_amdgcn_s_setprio(1);
#pragma unroll
    for (int m = 0; m < MFR; m++)
#pragma unroll
      for (int n = 0; n < 4; n++)
        acc[m][n] = __builtin_amdgcn_mfma_f32_16x16x32_bf16(af[m], bfr[n], acc[m][n], 0, 0, 0);
    __builtin_amdgcn_s_setprio(0);

    if (more) {
      if constexpr (BN == 128) asm volatile("s_waitcnt vmcnt(4)" ::: "memory");
      else                     asm volatile("s_waitcnt vmcnt(3)" ::: "memory");
    } else {
      asm volatile("s_waitcnt vmcnt(0)" ::: "memory");
    }
    __builtin_amdgcn_s_barrier();
    __builtin_amdgcn_sched_barrier(0);
  }

  const int r0 = bm0 + wm * (MFR * 16), c0 = bn0 + wn * 64;
  const int fg4 = (ln >> 4) * 4;
#pragma unroll
  for (int m = 0; m < MFR; m++)
#pragma unroll
    for (int n = 0; n < 4; n++)
#pragma unroll
      for (int j = 0; j < 4; j++) {
        int row = r0 + m * 16 + fg4 + j;
        int col = c0 + n * 16 + fln;
        float v = acc[m][n][j];
        if (col < scale_cols) v *= scale_val;
        if (F32OUT) ((float*)Cv)[(size_t)row * N + col] = v + bias[col];
        else        ((short*)Cv)[(size_t)row * N + col] = f2bf(v);
      }
}

// ---------------- flash attention: KV-split x2, 4 blocks/CU, static-max ----------------
// Grid 1024 (XCD-swizzled): c = bh*32 + qt*2 + kvs. 256 thr = 4 waves x 32 q-rows.
// Each block: 16 phases of 64 kv within its half. Partial O^T (bf16) + l (f32) out.
__global__ __launch_bounds__(256, 4) void attn_fwd(const short* __restrict__ QKV,
                                                   short* __restrict__ OP,
                                                   float* __restrict__ Lp) {
  __shared__ short Ks[2][64 * 64];   // [kv][d], XOR-swizzled 16B chunks
  __shared__ short Vt[2][64 * 64];   // [d][kv], XOR-swizzled
  const int tid = threadIdx.x, wv = tid >> 6, ln = tid & 63;
  const int lq = ln & 31, hi = ln >> 5;
  const int id = blockIdx.x;
  const int c = (id & 7) * 128 + (id >> 3);   // XCD swizzle: 4 heads per XCD
  const int kvs = c & 1, qt = (c >> 1) & 15, bh = c >> 5;
  const int b = bh >> 4, h = bh & 15;
  const short* base = QKV + (size_t)b * 2048 * 3072 + h * 64;
  const short* Kg = base + 1024 + (size_t)(kvs << 10) * 3072;
  const short* Vg = base + 2048 + (size_t)(kvs << 10) * 3072;
  const int qrow = qt * 128 + wv * 32 + lq;

  bf16x8 qf[4];
  {
    const short* Qrow = base + (size_t)qrow * 3072;
#pragma unroll
    for (int ds = 0; ds < 4; ds++)
      qf[ds] = *(const bf16x8*)(Qrow + ds * 16 + hi * 8);
  }

  // K staging: wave wv stages rows 16wv..16wv+15 (2 gload_lds chunks of 8 rows)
  const int krow = ln >> 3;                     // row within 8-row chunk
  const int kcol = ((ln & 7) ^ (ln >> 3)) * 8;  // pre-swizzled source col (shorts)
  // V staging: lane -> d-column ln; wave wv -> kv rows 16wv..16wv+15
  const int vrow_b = ln * 128;
  const int vxor = ln & 7;

  float l_run = 0.f;
  f32x16 o0 = {}, o1 = {};
  ushort_t vu[16];

  // prologue: stage tile 0
#pragma unroll
  for (int rd = 0; rd < 2; rd++)
    gload_lds16(Kg + (size_t)(16 * wv + 8 * rd + krow) * 3072 + kcol,
                (char*)Ks[0] + (2 * wv + rd) * 1024);
#pragma unroll
  for (int i = 0; i < 16; i++)
    vu[i] = *(const ushort_t*)(Vg + (size_t)(16 * wv + i) * 3072 + ln);
  {
    bf16x8 w0, w1;
#pragma unroll
    for (int i = 0; i < 8; i++) { w0[i] = (short)vu[i]; w1[i] = (short)vu[8 + i]; }
    *(bf16x8*)((char*)Vt[0] + vrow_b + (((2 * wv) ^ vxor) << 4)) = w0;
    *(bf16x8*)((char*)Vt[0] + vrow_b + (((2 * wv + 1) ^ vxor) << 4)) = w1;
  }
  __syncthreads();

  for (int t = 0; t < 16; t++) {
    const int s = t & 1;
    if (t < 15) {   // prefetch next tile
#pragma unroll
      for (int rd = 0; rd < 2; rd++)
        gload_lds16(Kg + (size_t)((t + 1) * 64 + 16 * wv + 8 * rd + krow) * 3072 + kcol,
                    (char*)Ks[s ^ 1] + (2 * wv + rd) * 1024);
#pragma unroll
      for (int i = 0; i < 16; i++)
        vu[i] = *(const ushort_t*)(Vg + (size_t)((t + 1) * 64 + 16 * wv + i) * 3072 + ln);
    }

    // S^T = K Q^T (log2-domain scores; q pre-scaled by 0.125*log2e)
    f32x16 c0 = {}, c1 = {};
    const char* Kb = (const char*)Ks[s];
    __builtin_amdgcn_s_setprio(1);
#pragma unroll
    for (int ds = 0; ds < 4; ds++) {
      const int cp = (ds * 2 + hi) ^ (lq & 7);
      bf16x8 ka0 = *(const bf16x8*)(Kb + lq * 128 + cp * 16);
      bf16x8 ka1 = *(const bf16x8*)(Kb + (32 + lq) * 128 + cp * 16);
      c0 = __builtin_amdgcn_mfma_f32_32x32x16_bf16(ka0, qf[ds], c0, 0, 0, 0);
      c1 = __builtin_amdgcn_mfma_f32_32x32x16_bf16(ka1, qf[ds], c1, 0, 0, 0);
    }
    __builtin_amdgcn_s_setprio(0);

    // static-max softmax: p = exp2(s) directly (2^m cancels in (O0+O1)/(l0+l1))
#pragma unroll
    for (int r = 0; r < 16; r++) c0[r] = __builtin_amdgcn_exp2f(c0[r]);
#pragma unroll
    for (int r = 0; r < 16; r++) c1[r] = __builtin_amdgcn_exp2f(c1[r]);
    {
      float st[8];
#pragma unroll
      for (int r = 0; r < 8; r++)
        st[r] = (c0[2 * r] + c0[2 * r + 1]) + (c1[2 * r] + c1[2 * r + 1]);
#pragma unroll
      for (int r = 0; r < 4; r++) st[r] += st[r + 4];
      l_run += (st[0] + st[1]) + (st[2] + st[3]);
    }

    // T12: P^T B-fragments in-register
    bf16x8 pa[4];
#pragma unroll
    for (int cs = 0; cs < 2; cs++) {
      const f32x16& p = cs ? c1 : c0;
#pragma unroll
      for (int ksl = 0; ksl < 2; ksl++) {
        unsigned A0 = cvtpk(p[8 * ksl + 0], p[8 * ksl + 1]);
        unsigned A1 = cvtpk(p[8 * ksl + 2], p[8 * ksl + 3]);
        unsigned B0 = cvtpk(p[8 * ksl + 4], p[8 * ksl + 5]);
        unsigned B1 = cvtpk(p[8 * ksl + 6], p[8 * ksl + 7]);
        swap32u(A0, B0);
        swap32u(A1, B1);
        union { unsigned u[4]; bf16x8 v; } tmp;
        tmp.u[0] = A0; tmp.u[1] = A1; tmp.u[2] = B0; tmp.u[3] = B1;
        pa[cs * 2 + ksl] = tmp.v;
      }
    }

    // O^T += V^T P^T
    const char* Vb = (const char*)Vt[s];
    __builtin_amdgcn_s_setprio(1);
#pragma unroll
    for (int ks = 0; ks < 4; ks++) {
      const int cp = (ks * 2 + hi) ^ (lq & 7);
      bf16x8 va0 = *(const bf16x8*)(Vb + lq * 128 + cp * 16);
      bf16x8 va1 = *(const bf16x8*)(Vb + (32 + lq) * 128 + cp * 16);
      o0 = __builtin_amdgcn_mfma_f32_32x32x16_bf16(va0, pa[ks], o0, 0, 0, 0);
      o1 = __builtin_amdgcn_mfma_f32_32x32x16_bf16(va1, pa[ks], o1, 0, 0, 0);
    }
    __builtin_amdgcn_s_setprio(0);

    if (t < 15) {   // late V write into next buffer
      bf16x8 w0, w1;
#pragma unroll
      for (int i = 0; i < 8; i++) { w0[i] = (short)vu[i]; w1[i] = (short)vu[8 + i]; }
      *(bf16x8*)((char*)Vt[s ^ 1] + vrow_b + (((2 * wv) ^ vxor) << 4)) = w0;
      *(bf16x8*)((char*)Vt[s ^ 1] + vrow_b + (((2 * wv + 1) ^ vxor) << 4)) = w1;
    }
    __syncthreads();
  }

  // epilogue: partial l (once per q) + partial O^T as bf16, layout OP[c][q=128][d=64]
  l_run += __shfl_xor(l_run, 32);
  const int qcol = wv * 32 + lq;
  if (hi == 0) Lp[c * 128 + qcol] = l_run;
  short* Op = OP + (size_t)c * 8192 + qcol * 64;
#pragma unroll
  for (int dt = 0; dt < 2; dt++) {
    const f32x16& o = dt ? o1 : o0;
#pragma unroll
    for (int g = 0; g < 4; g++) {
      bf16x4 w;
#pragma unroll
      for (int i = 0; i < 4; i++) w[i] = f2bf(o[4 * g + i]);
      *(bf16x4*)(Op + dt * 32 + 8 * g + 4 * hi) = w;
    }
  }
}

// ---------------- merge the two KV-half partials into AO ----------------
// Grid 512 (bh*16+qt), 256 thr: tid -> q = tid&127, d-half = tid>>7.
__global__ __launch_bounds__(256) void attn_merge(const short* __restrict__ OP,
                                                  const float* __restrict__ Lp,
                                                  short* __restrict__ AO) {
  const int m = blockIdx.x;
  const int bh = m >> 4, qt = m & 15;
  const int b = bh >> 4, h = bh & 15;
  const int tid = threadIdx.x;
  const int q = tid & 127, dh = tid >> 7;
  const int c0 = bh * 32 + qt * 2, c1 = c0 + 1;
  const float l = Lp[c0 * 128 + q] + Lp[c1 * 128 + q];
  const float inv = __builtin_amdgcn_rcpf(l);
  const short* p0 = OP + (size_t)c0 * 8192 + q * 64 + dh * 32;
  const short* p1 = OP + (size_t)c1 * 8192 + q * 64 + dh * 32;
  short* dst = AO + ((size_t)(b * 2048 + qt * 128 + q)) * 1024 + h * 64 + dh * 32;
#pragma unroll
  for (int v = 0; v < 4; v++) {
    bf16x8 a = ((const bf16x8*)p0)[v];
    bf16x8 bb = ((const bf16x8*)p1)[v];
    bf16x8 w;
#pragma unroll
    for (int j = 0; j < 8; j++)
      w[j] = f2bf((bf2f(a[j]) + bf2f(bb[j])) * inv);
    ((bf16x8*)dst)[v] = w;
  }
}

// ---------------- launch ----------------
extern "C" void kernel_launch(void* const* d_in, const int* in_sizes, int n_in,
                              void* d_out, int out_size, void* d_ws, size_t ws_size,
                              hipStream_t stream) {
  const float* x = (const float*)d_in[0];       // [2,2048,1024]
  const float* w_qkv = (const float*)d_in[1];   // [3072,1024]
  const float* w_proj = (const float*)d_in[2];  // [1024,1024]
  const float* b_proj = (const float*)d_in[3];  // [1024]
  float* out = (float*)d_out;                   // [2,2048,1024] fp32

  char* ws = (char*)d_ws;
  short* Xb = (short*)(ws + 0);                  //  8 MB  [4096][1024]
  short* Wq = (short*)(ws + 8388608);            //  6 MB  [3072][1024]
  short* Wp = (short*)(ws + 14680064);           //  2 MB  [1024][1024]
  short* QKV = (short*)(ws + 16777216);          // 24 MB  [4096][3072]
  short* AO = (short*)(ws + 41943040);           //  8 MB  [4096][1024]
  float* Lp = (float*)(ws + 50331648);           // 0.5 MB [1024][128]
  short* OP = (short*)d_out;                     // 16 MB partial O^T (overwritten by proj)

  cvt_all<<<4096, 256, 0, stream>>>(x, w_qkv, w_proj, Xb, Wq, Wp);

  // qkv GEMM: q columns (<1024) pre-scaled for exp2-domain softmax
  gemm_pipe<128, 0><<<dim3(24, 32), 256, 0, stream>>>(Xb, Wq, QKV, nullptr,
                                                      1024, QSCALE, 4096, 3072, 1024);

  attn_fwd<<<dim3(1024), 256, 0, stream>>>(QKV, OP, Lp);
  attn_merge<<<dim3(512), 256, 0, stream>>>(OP, Lp, AO);

  gemm_pipe<64, 1><<<dim3(16, 32), 256, 0, stream>>>(AO, Wp, out, b_proj,
                                                     0, 1.0f, 4096, 1024, 1024);
}

// Round 8
// 114.400 us; speedup vs baseline: 1.1163x; 1.1163x over previous
//
#include <hip/hip_runtime.h>
#include <hip/hip_bf16.h>
#include <stdint.h>

typedef __attribute__((ext_vector_type(4))) float f32x4;
typedef __attribute__((ext_vector_type(16))) float f32x16;
typedef __attribute__((ext_vector_type(8))) short bf16x8;
typedef __attribute__((ext_vector_type(4))) short bf16x4;
typedef unsigned short ushort_t;

#define QSCALE 0.18033688f   // 0.125 * log2(e): softmax runs in exp2 domain

__device__ inline short f2bf(float f) {
  unsigned u = __builtin_bit_cast(unsigned, f);
  u += 0x7fffu + ((u >> 16) & 1u);   // RNE
  return (short)(u >> 16);
}

__device__ inline void gload_lds16(const void* g, void* l) {
  __builtin_amdgcn_global_load_lds(
      (const __attribute__((address_space(1))) void*)g,
      (__attribute__((address_space(3))) void*)l, 16, 0, 0);
}

__device__ inline unsigned cvtpk(float a, float b) {
  unsigned r;
  asm("v_cvt_pk_bf16_f32 %0, %1, %2" : "=v"(r) : "v"(a), "v"(b));
  return r;
}

__device__ inline void swap32u(unsigned& a, unsigned& b) {
  asm("v_permlane32_swap_b32 %0, %1" : "+v"(a), "+v"(b));
}

// ---------------- fused fp32 -> bf16 convert (x, w_qkv, w_proj) ----------------
__global__ __launch_bounds__(256) void cvt_all(const float* __restrict__ x,
                                               const float* __restrict__ wq,
                                               const float* __restrict__ wp,
                                               short* __restrict__ Xb,
                                               short* __restrict__ Wq,
                                               short* __restrict__ Wp) {
  int i = blockIdx.x * 256 + threadIdx.x;   // vec8 index, total 1048576
  const float* s;
  short* d;
  int off;
  if (i < 524288)       { s = x;  d = Xb; off = i; }
  else if (i < 917504)  { s = wq; d = Wq; off = i - 524288; }
  else                  { s = wp; d = Wp; off = i - 917504; }
  const float4* sv = (const float4*)s;
  float4 a = sv[2 * off], b = sv[2 * off + 1];
  bf16x8 o;
  o[0] = f2bf(a.x); o[1] = f2bf(a.y); o[2] = f2bf(a.z); o[3] = f2bf(a.w);
  o[4] = f2bf(b.x); o[5] = f2bf(b.y); o[6] = f2bf(b.z); o[7] = f2bf(b.w);
  ((bf16x8*)d)[off] = o;
}

// ---------------- 128xBN BK=32 3-buffer counted-vmcnt GEMM: C = A * B^T ----------------
// SPLITV=1 (qkv): cols<2048 -> QK[4096][2048] bf16 (q cols<1024 pre-scaled);
//                 cols>=2048 -> Vtg[(b*16+h)*64+d][2048] bf16 (transposed V).
// SPLITV=0: F32OUT? fp32+bias : bf16, stride N.
template <int BN, int F32OUT, int SPLITV>
__global__ __launch_bounds__(256, 3) void gemm_pipe(const short* __restrict__ A,
                                                    const short* __restrict__ B,
                                                    void* __restrict__ Cv,
                                                    short* __restrict__ Vtg,
                                                    const float* __restrict__ bias,
                                                    int scale_cols, float scale_val,
                                                    int M, int N, int K) {
  constexpr int MFR = (BN == 128) ? 4 : 2;
  __shared__ short Abuf[3][128 * 32];
  __shared__ short Bbuf[3][BN * 32];
  const int tid = threadIdx.x, wv = tid >> 6, ln = tid & 63;
  const int wm = (BN == 128) ? (wv >> 1) : wv;
  const int wn = (BN == 128) ? (wv & 1) : 0;
  const int bn0 = blockIdx.x * BN, bm0 = blockIdx.y * 128;
  const int nt = K >> 5;

  const int srow = ln >> 2;
  const int scol = (((ln & 3) ^ (srow & 3)) * 8);
  const int fln = ln & 15;
  const int fk = ln >> 4;

  f32x4 acc[MFR][4] = {};

  auto stage = [&](int t, int s) {
    const size_t k0 = (size_t)(t << 5);
#pragma unroll
    for (int rd = 0; rd < 2; rd++) {
      int ch = 2 * wv + rd;
      gload_lds16(A + (size_t)(bm0 + ch * 16 + srow) * K + k0 + scol,
                  (char*)Abuf[s] + ch * 1024);
    }
    if constexpr (BN == 128) {
#pragma unroll
      for (int rd = 0; rd < 2; rd++) {
        int ch = 2 * wv + rd;
        gload_lds16(B + (size_t)(bn0 + ch * 16 + srow) * K + k0 + scol,
                    (char*)Bbuf[s] + ch * 1024);
      }
    } else {
      gload_lds16(B + (size_t)(bn0 + wv * 16 + srow) * K + k0 + scol,
                  (char*)Bbuf[s] + wv * 1024);
    }
  };

  stage(0, 0);
  stage(1, 1);
  if constexpr (BN == 128) asm volatile("s_waitcnt vmcnt(4)" ::: "memory");
  else                     asm volatile("s_waitcnt vmcnt(3)" ::: "memory");
  __builtin_amdgcn_s_barrier();
  __builtin_amdgcn_sched_barrier(0);

  for (int t = 0; t < nt; t++) {
    const int s = t % 3;
    const bool more = (t + 2) < nt;
    if (more) stage(t + 2, (t + 2) % 3);

    const char* Ab = (const char*)Abuf[s];
    const char* Bb = (const char*)Bbuf[s];
    bf16x8 af[MFR], bfr[4];
#pragma unroll
    for (int m = 0; m < MFR; m++) {
      int R = wm * (MFR * 16) + m * 16 + fln;
      af[m] = *(const bf16x8*)(Ab + R * 64 + ((fk ^ (R & 3)) << 4));
    }
#pragma unroll
    for (int n = 0; n < 4; n++) {
      int R = wn * 64 + n * 16 + fln;
      bfr[n] = *(const bf16x8*)(Bb + R * 64 + ((fk ^ (R & 3)) << 4));
    }

    __builtin_amdgcn_s_setprio(1);
#pragma unroll
    for (int m = 0; m < MFR; m++)
#pragma unroll
      for (int n = 0; n < 4; n++)
        acc[m][n] = __builtin_amdgcn_mfma_f32_16x16x32_bf16(af[m], bfr[n], acc[m][n], 0, 0, 0);
    __builtin_amdgcn_s_setprio(0);

    if (more) {
      if constexpr (BN == 128) asm volatile("s_waitcnt vmcnt(4)" ::: "memory");
      else                     asm volatile("s_waitcnt vmcnt(3)" ::: "memory");
    } else {
      asm volatile("s_waitcnt vmcnt(0)" ::: "memory");
    }
    __builtin_amdgcn_s_barrier();
    __builtin_amdgcn_sched_barrier(0);
  }

  const int r0 = bm0 + wm * (MFR * 16), c0 = bn0 + wn * 64;
  const int fg4 = (ln >> 4) * 4;
#pragma unroll
  for (int m = 0; m < MFR; m++) {
    const int row0 = r0 + m * 16 + fg4;
#pragma unroll
    for (int n = 0; n < 4; n++) {
      const int col = c0 + n * 16 + fln;
      if constexpr (SPLITV) {
        if (col < 2048) {
          const float sc = (col < scale_cols) ? scale_val : 1.0f;
#pragma unroll
          for (int j = 0; j < 4; j++)
            ((short*)Cv)[(size_t)(row0 + j) * 2048 + col] = f2bf(acc[m][n][j] * sc);
        } else {
          const int f = col - 2048, h = f >> 6, d = f & 63;
          const int bb = row0 >> 11, ntok = row0 & 2047;
          bf16x4 w;
#pragma unroll
          for (int j = 0; j < 4; j++) w[j] = f2bf(acc[m][n][j]);
          *(bf16x4*)(Vtg + ((size_t)((bb * 16 + h) * 64 + d)) * 2048 + ntok) = w;
        }
      } else {
#pragma unroll
        for (int j = 0; j < 4; j++) {
          float v = acc[m][n][j];
          if (col < scale_cols) v *= scale_val;
          if (F32OUT) ((float*)Cv)[(size_t)(row0 + j) * N + col] = v + bias[col];
          else        ((short*)Cv)[(size_t)(row0 + j) * N + col] = f2bf(v);
        }
      }
    }
  }
}

// ---------------- flash attention: K and V^T both via global_load_lds ----------------
// QK: [4096][2048] bf16 (q pre-scaled, k at +1024). Vtg: [(b*16+h)*64+d][2048] bf16.
// Grid 512 (XCD-swizzled), 256 thr = 4 waves x 32 q-rows. 32 tiles of 64 kv.
__global__ __launch_bounds__(256, 2) void attn_fwd(const short* __restrict__ QK,
                                                   const short* __restrict__ Vtg,
                                                   short* __restrict__ AO) {
  __shared__ short Ks[2][64 * 64];   // [kv][d], XOR-swizzled 16B chunks
  __shared__ short Vt[2][64 * 64];   // [d][kv], XOR-swizzled (staged from Vtg)
  const int tid = threadIdx.x, wv = tid >> 6, ln = tid & 63;
  const int lq = ln & 31, hi = ln >> 5;
  const int id = blockIdx.x;
  const int c = (id & 7) * 64 + (id >> 3);   // XCD swizzle: 4 heads per XCD
  const int qt = c & 15, bh = c >> 4;
  const int b = bh >> 4, h = bh & 15;
  const short* base = QK + (size_t)(b * 2048) * 2048 + h * 64;
  const short* Kg = base + 1024;
  const short* Vg = Vtg + (size_t)bh * 64 * 2048;   // rows d, cols token
  const int qrow = qt * 128 + wv * 32 + lq;

  bf16x8 qf[4];
  {
    const short* Qrow = base + (size_t)qrow * 2048;
#pragma unroll
    for (int ds = 0; ds < 4; ds++)
      qf[ds] = *(const bf16x8*)(Qrow + ds * 16 + hi * 8);
  }

  // staging pattern (shared by K and V^T): wave wv stages rows 16wv..16wv+15
  // (2 chunks of 8 rows); lane -> row ln>>3 in chunk, pre-swizzled col chunk.
  const int krow = ln >> 3;
  const int kcol = ((ln & 7) ^ (ln >> 3)) * 8;   // shorts

  float l_run = 0.f;
  f32x16 o0 = {}, o1 = {};

#define STAGE(t, s)                                                              \
  {                                                                              \
    _Pragma("unroll")                                                            \
    for (int rd = 0; rd < 2; rd++) {                                             \
      const int r8 = 16 * wv + 8 * rd + krow;                                    \
      gload_lds16(Kg + (size_t)((t) * 64 + r8) * 2048 + kcol,                    \
                  (char*)Ks[s] + (2 * wv + rd) * 1024);                          \
      gload_lds16(Vg + (size_t)r8 * 2048 + (t) * 64 + kcol,                      \
                  (char*)Vt[s] + (2 * wv + rd) * 1024);                          \
    }                                                                            \
  }

  STAGE(0, 0);
  __syncthreads();

  for (int t = 0; t < 32; t++) {
    const int s = t & 1;
    if (t < 31) STAGE(t + 1, s ^ 1);   // prefetch next tile (drained at end barrier)

    // S^T = K Q^T (log2-domain scores; q pre-scaled by 0.125*log2e)
    f32x16 c0 = {}, c1 = {};
    const char* Kb = (const char*)Ks[s];
    __builtin_amdgcn_s_setprio(1);
#pragma unroll
    for (int ds = 0; ds < 4; ds++) {
      const int cp = (ds * 2 + hi) ^ (lq & 7);
      bf16x8 ka0 = *(const bf16x8*)(Kb + lq * 128 + cp * 16);
      bf16x8 ka1 = *(const bf16x8*)(Kb + (32 + lq) * 128 + cp * 16);
      c0 = __builtin_amdgcn_mfma_f32_32x32x16_bf16(ka0, qf[ds], c0, 0, 0, 0);
      c1 = __builtin_amdgcn_mfma_f32_32x32x16_bf16(ka1, qf[ds], c1, 0, 0, 0);
    }
    __builtin_amdgcn_s_setprio(0);

    // static-max softmax: p = exp2(s) directly (2^m cancels in O/l)
#pragma unroll
    for (int r = 0; r < 16; r++) c0[r] = __builtin_amdgcn_exp2f(c0[r]);
#pragma unroll
    for (int r = 0; r < 16; r++) c1[r] = __builtin_amdgcn_exp2f(c1[r]);
    {
      float st[8];
#pragma unroll
      for (int r = 0; r < 8; r++)
        st[r] = (c0[2 * r] + c0[2 * r + 1]) + (c1[2 * r] + c1[2 * r + 1]);
#pragma unroll
      for (int r = 0; r < 4; r++) st[r] += st[r + 4];
      l_run += (st[0] + st[1]) + (st[2] + st[3]);
    }

    // T12: P^T B-fragments in-register
    bf16x8 pa[4];
#pragma unroll
    for (int cs = 0; cs < 2; cs++) {
      const f32x16& p = cs ? c1 : c0;
#pragma unroll
      for (int ksl = 0; ksl < 2; ksl++) {
        unsigned A0 = cvtpk(p[8 * ksl + 0], p[8 * ksl + 1]);
        unsigned A1 = cvtpk(p[8 * ksl + 2], p[8 * ksl + 3]);
        unsigned B0 = cvtpk(p[8 * ksl + 4], p[8 * ksl + 5]);
        unsigned B1 = cvtpk(p[8 * ksl + 6], p[8 * ksl + 7]);
        swap32u(A0, B0);
        swap32u(A1, B1);
        union { unsigned u[4]; bf16x8 v; } tmp;
        tmp.u[0] = A0; tmp.u[1] = A1; tmp.u[2] = B0; tmp.u[3] = B1;
        pa[cs * 2 + ksl] = tmp.v;
      }
    }

    // O^T += V^T P^T  (V^T fragments read same pattern as K)
    const char* Vb = (const char*)Vt[s];
    __builtin_amdgcn_s_setprio(1);
#pragma unroll
    for (int ks = 0; ks < 4; ks++) {
      const int cp = (ks * 2 + hi) ^ (lq & 7);
      bf16x8 va0 = *(const bf16x8*)(Vb + lq * 128 + cp * 16);
      bf16x8 va1 = *(const bf16x8*)(Vb + (32 + lq) * 128 + cp * 16);
      o0 = __builtin_amdgcn_mfma_f32_32x32x16_bf16(va0, pa[ks], o0, 0, 0, 0);
      o1 = __builtin_amdgcn_mfma_f32_32x32x16_bf16(va1, pa[ks], o1, 0, 0, 0);
    }
    __builtin_amdgcn_s_setprio(0);

    __syncthreads();
  }
#undef STAGE

  // epilogue: combine lane halves of l once, then AO = O^T / l
  l_run += __shfl_xor(l_run, 32);
  const float inv = __builtin_amdgcn_rcpf(l_run);
  short* Arow = AO + ((size_t)(b * 2048) + qrow) * 1024 + h * 64;
#pragma unroll
  for (int dt = 0; dt < 2; dt++) {
    const f32x16& o = dt ? o1 : o0;
#pragma unroll
    for (int g = 0; g < 4; g++) {
      bf16x4 w;
#pragma unroll
      for (int i = 0; i < 4; i++) w[i] = f2bf(o[4 * g + i] * inv);
      *(bf16x4*)(Arow + dt * 32 + 8 * g + 4 * hi) = w;
    }
  }
}

// ---------------- launch ----------------
extern "C" void kernel_launch(void* const* d_in, const int* in_sizes, int n_in,
                              void* d_out, int out_size, void* d_ws, size_t ws_size,
                              hipStream_t stream) {
  const float* x = (const float*)d_in[0];       // [2,2048,1024]
  const float* w_qkv = (const float*)d_in[1];   // [3072,1024]
  const float* w_proj = (const float*)d_in[2];  // [1024,1024]
  const float* b_proj = (const float*)d_in[3];  // [1024]
  float* out = (float*)d_out;                   // [2,2048,1024] fp32

  char* ws = (char*)d_ws;
  short* Xb  = (short*)(ws + 0);                 //  8 MB  [4096][1024]
  short* Wq  = (short*)(ws + 8388608);           //  6 MB  [3072][1024]
  short* Wp  = (short*)(ws + 14680064);          //  2 MB  [1024][1024]
  short* QK  = (short*)(ws + 16777216);          // 16 MB  [4096][2048]
  short* Vtg = (short*)(ws + 33554432);          //  8 MB  [32*64][2048]
  short* AO  = (short*)(ws + 41943040);          //  8 MB  [4096][1024]

  cvt_all<<<4096, 256, 0, stream>>>(x, w_qkv, w_proj, Xb, Wq, Wp);

  // qkv GEMM: q cols (<1024) pre-scaled; k -> QK[:,1024:]; v -> Vtg transposed
  gemm_pipe<128, 0, 1><<<dim3(24, 32), 256, 0, stream>>>(Xb, Wq, QK, Vtg, nullptr,
                                                         1024, QSCALE, 4096, 3072, 1024);

  attn_fwd<<<dim3(512), 256, 0, stream>>>(QK, Vtg, AO);

  gemm_pipe<64, 1, 0><<<dim3(16, 32), 256, 0, stream>>>(AO, Wp, out, nullptr, b_proj,
                                                        0, 1.0f, 4096, 1024, 1024);
}